// Round 10
// baseline (202.561 us; speedup 1.0000x reference)
//
#include <hip/hip_runtime.h>
#include <hip/hip_bf16.h>
#include <math.h>

#define D512 512
#define NTOK 1024
#define QSCALE 0.1803368801111137f   // 0.125 * log2(e): folded into q-projection

typedef __attribute__((ext_vector_type(8))) short short8;
typedef __attribute__((ext_vector_type(4))) float f32x4;
typedef __attribute__((ext_vector_type(16))) float f32x16;
typedef __attribute__((ext_vector_type(4))) unsigned int u32x4;
typedef unsigned short ushort;

__device__ inline ushort f2bf(float x) {
    union { float f; unsigned u; } a; a.f = x;
    unsigned r = a.u + 0x7FFF + ((a.u >> 16) & 1);   // RNE
    return (ushort)(r >> 16);
}

// packed RNE f32x2 -> bf16x2 (lo = a, hi = b)
__device__ inline unsigned cvtpk(float a, float b) {
    unsigned r;
    asm volatile("v_cvt_pk_bf16_f32 %0, %1, %2" : "=v"(r) : "v"(a), "v"(b));
    return r;
}

// v_permlane32_swap_b32: a.row1 <-> b.row0  =>  a' = [A0|B0], b' = [A1|B1]
__device__ inline void plswap(unsigned &a, unsigned &b) {
    asm volatile("v_permlane32_swap_b32 %0, %1" : "+v"(a), "+v"(b));
}

// global -> LDS direct (16B/lane). dst wave-uniform; src per-lane.
#define GLL16(src, dst) __builtin_amdgcn_global_load_lds( \
    (const __attribute__((address_space(1))) unsigned int*)(src), \
    (__attribute__((address_space(3))) unsigned int*)(dst), 16, 0, 0)

// ---------------------------------------------------------------------------
// hs (fp32) -> bf16
// ---------------------------------------------------------------------------
__global__ __launch_bounds__(256) void cvt_bf16(
    const float* __restrict__ in, ushort* __restrict__ out)
{
    const int idx = blockIdx.x * 256 + threadIdx.x;
    float4 a = ((const float4*)in)[idx * 2];
    float4 b = ((const float4*)in)[idx * 2 + 1];
    short8 s;
    s[0] = f2bf(a.x); s[1] = f2bf(a.y); s[2] = f2bf(a.z); s[3] = f2bf(a.w);
    s[4] = f2bf(b.x); s[5] = f2bf(b.y); s[6] = f2bf(b.z); s[7] = f2bf(b.w);
    *(short8*)&out[(size_t)idx * 8] = s;
}

// ---------------------------------------------------------------------------
// Fold LoRA into weights AND transpose: WT[e][d] bf16 (4 matrices: q,k,v,o)
// ---------------------------------------------------------------------------
__global__ __launch_bounds__(256) void fold_weights_T(
    const float* __restrict__ Wq, const float* __restrict__ Wk,
    const float* __restrict__ Wv, const float* __restrict__ Wo,
    const float* __restrict__ qd, const float* __restrict__ qu,
    const float* __restrict__ kd, const float* __restrict__ ku,
    const float* __restrict__ vd, const float* __restrict__ vu,
    const float* __restrict__ od, const float* __restrict__ ou,
    ushort* __restrict__ out)
{
    const int which = blockIdx.y;
    const float *W, *dn, *up;
    if (which == 0)      { W = Wq; dn = qd; up = qu; }
    else if (which == 1) { W = Wk; dn = kd; up = ku; }
    else if (which == 2) { W = Wv; dn = vd; up = vu; }
    else                 { W = Wo; dn = od; up = ou; }

    const int td = (blockIdx.x >> 3) * 64;
    const int te = (blockIdx.x & 7) * 64;
    __shared__ float T[64][65];
    const int r4 = threadIdx.x >> 6;
    const int c  = threadIdx.x & 63;

    #pragma unroll
    for (int i = 0; i < 16; ++i) {
        int row = i * 4 + r4;
        T[row][c] = W[(size_t)(td + row) * 512 + te + c];
    }
    __syncthreads();
    #pragma unroll
    for (int i = 0; i < 16; ++i) {
        int e = te + i * 4 + r4;
        int d = td + c;
        float s = T[c][i * 4 + r4];
        #pragma unroll
        for (int r = 0; r < 4; ++r) s += dn[d * 4 + r] * up[r * 512 + e];
        out[(size_t)which * 262144 + (size_t)e * 512 + d] = f2bf(s);
    }
}

// ---------------------------------------------------------------------------
// bf16 MFMA GEMM, 128x128 tile, BK=32, 4 waves, double-buffered LDS (32 KB),
// single __syncthreads per K-step (r7-proven structure).
// 1-D grid, XCD-aware decode (wgid%8 = m-panel residue).
// QKV=1 (grid 3072): q -> qb [bh][n][64]*QSCALE, k -> kb (both via coalesced
//   LDS-transpose epilogue: b128 dense stores), v -> vtb [bh][d][n].
// QKV=0 (grid 1024): fp32 + bias -> Co [row][512]
// ---------------------------------------------------------------------------
#define SWZT(r, c) ((((r) * 128) + (c)) ^ (((r) & 7) << 3))

template<int QKV>
__global__ __launch_bounds__(256) void gemm_mfma(
    const ushort* __restrict__ A, const ushort* __restrict__ BT,
    const float* __restrict__ bias, float* __restrict__ Co,
    ushort* __restrict__ qb, ushort* __restrict__ kb, ushort* __restrict__ vtb)
{
    __shared__ ushort smem[16384];   // 2 x (As 4096 + Bs 4096); epilogue reuses [0..8192)

    const int tid = threadIdx.x;
    const int w = tid >> 6, l = tid & 63;
    const int l15 = l & 15, l4 = l >> 4;

    // XCD-aware decode
    const int wg = blockIdx.x;
    const int rxcd = wg & 7, t = wg >> 3;
    const int NX = QKV ? 12 : 4;
    const int xb = t % NX, yh = t / NX;          // yh 0..31
    const int yb = (yh << 3) | rxcd;             // m-tile 0..255
    const int m0 = yb * 128;
    const int n0 = xb * 128;

    const int srow = l >> 2;
    const int scol = (l & 3) * 8;
    const ushort* Asrc = A  + (size_t)(m0 + w * 32 + srow) * 512 + scol;
    const ushort* Bsrc = BT + (size_t)(n0 + w * 32 + srow) * 512 + scol;

    const int wm = (w >> 1) * 64, wn = (w & 1) * 64;

    f32x4 acc[4][4] = {};

    {   // prologue: stage k0 = 0 into buf 0
        ushort* AsW = smem + w * 1024;
        ushort* BsW = smem + 4096 + w * 1024;
        GLL16(Asrc, AsW);            GLL16(Asrc + 16 * 512, AsW + 512);
        GLL16(Bsrc, BsW);            GLL16(Bsrc + 16 * 512, BsW + 512);
    }
    __syncthreads();

    int cur = 0;
    for (int k0 = 0; k0 < 512; k0 += 32) {
        if (k0 < 480) {
            ushort* AsW = smem + (cur ^ 1) * 8192 + w * 1024;
            ushort* BsW = smem + (cur ^ 1) * 8192 + 4096 + w * 1024;
            GLL16(Asrc + k0 + 32, AsW);
            GLL16(Asrc + k0 + 32 + 16 * 512, AsW + 512);
            GLL16(Bsrc + k0 + 32, BsW);
            GLL16(Bsrc + k0 + 32 + 16 * 512, BsW + 512);
        }
        const ushort* As = smem + cur * 8192;
        const ushort* Bs = smem + cur * 8192 + 4096;

        short8 bfr[4];
        #pragma unroll
        for (int ni = 0; ni < 4; ++ni)
            bfr[ni] = *(const short8*)&Bs[(wn + ni * 16 + l15) * 32 + l4 * 8];
        __builtin_amdgcn_s_setprio(1);
        #pragma unroll
        for (int mi = 0; mi < 4; ++mi) {
            short8 af = *(const short8*)&As[(wm + mi * 16 + l15) * 32 + l4 * 8];
            #pragma unroll
            for (int ni = 0; ni < 4; ++ni)
                acc[mi][ni] = __builtin_amdgcn_mfma_f32_16x16x32_bf16(
                    af, bfr[ni], acc[mi][ni], 0, 0, 0);
        }
        __builtin_amdgcn_s_setprio(0);
        __syncthreads();
        cur ^= 1;
    }

    if (QKV) {
        const int which = xb >> 2;               // 0=q 1=k 2=v
        if (which < 2) {
            // ---- coalesced LDS-transpose epilogue for q/k ----
            const float sc = which ? 1.0f : QSCALE;
            ushort* dst = which ? kb : qb;
            const int headbase = (n0 & 511) >> 6;     // even
            #pragma unroll
            for (int h = 0; h < 2; ++h) {
                if (wm == h * 64) {
                    #pragma unroll
                    for (int mi = 0; mi < 4; ++mi)
                        #pragma unroll
                        for (int j = 0; j < 4; ++j) {
                            const int r = mi * 16 + l4 * 4 + j;
                            #pragma unroll
                            for (int ni = 0; ni < 4; ++ni) {
                                const int c = wn + ni * 16 + l15;
                                smem[SWZT(r, c)] = f2bf(acc[mi][ni][j] * sc);
                            }
                        }
                }
                __syncthreads();
                const int rr2 = tid >> 4;         // 0..15
                const int cc2 = (tid & 15) * 8;   // 0..120
                const int chunk = cc2 >> 6;       // 0 or 1 (head within tile)
                const int d0 = cc2 & 63;
                #pragma unroll
                for (int s = 0; s < 4; ++s) {
                    const int r = s * 16 + rr2;
                    const int token = m0 + h * 64 + r;
                    const size_t off = (((size_t)(token >> 10) * 8 + headbase + chunk)
                                        * NTOK + (token & 1023)) * 64 + d0;
                    *(u32x4*)&dst[off] = *(const u32x4*)&smem[SWZT(r, cc2)];
                }
                if (h == 0) __syncthreads();
            }
        } else {
            #pragma unroll
            for (int mi = 0; mi < 4; ++mi) {
                const int rowb = m0 + wm + mi * 16 + l4 * 4;
                const int nn = rowb & 1023;
                const int bf8 = (rowb >> 10) * 8;
                #pragma unroll
                for (int ni = 0; ni < 4; ++ni) {
                    const int col = (n0 & 511) + wn + ni * 16 + l15;
                    const int d = col & 63, head = (col >> 6) & 7;
                    unsigned w0 = cvtpk(acc[mi][ni][0], acc[mi][ni][1]);
                    unsigned w1 = cvtpk(acc[mi][ni][2], acc[mi][ni][3]);
                    *(unsigned long long*)&vtb[((size_t)(bf8 + head) * 64 + d) * NTOK + nn] =
                        (unsigned long long)w0 | ((unsigned long long)w1 << 32);
                }
            }
        }
    } else {
        float bvals[4];
        #pragma unroll
        for (int ni = 0; ni < 4; ++ni)
            bvals[ni] = bias[n0 + wn + ni * 16 + l15];
        #pragma unroll
        for (int mi = 0; mi < 4; ++mi)
            #pragma unroll
            for (int j = 0; j < 4; ++j) {
                const int row = m0 + wm + mi * 16 + l4 * 4 + j;
                #pragma unroll
                for (int ni = 0; ni < 4; ++ni) {
                    const int col = n0 + wn + ni * 16 + l15;
                    Co[(size_t)row * 512 + col] = acc[mi][ni][j] + bvals[ni];
                }
            }
    }
}

// ---------------------------------------------------------------------------
// 32x32 swapped-operand MFMA flash attention (r7 verbatim — last known pass).
// Two q-tiles per wave; K/V double-buffered via GLL16; no-max exp2 softmax;
// permlane32 half-exchange; XCD-aware grid.
// ---------------------------------------------------------------------------
#define SWZ(r, c) ((((r) * 64) + (c)) ^ (((r) & 7) << 3))

// softmax (no-max, exp2 domain) + bf16 pack + half-exchange -> PV A-operand
#define SOFTPACK(sv0, sv1, lsum, pa) { \
    unsigned pk[2][4][2]; \
    float ls = 0.f; \
    _Pragma("unroll") \
    for (int rq = 0; rq < 4; ++rq) { \
        float p0 = __builtin_amdgcn_exp2f(sv0[4 * rq + 0]); \
        float p1 = __builtin_amdgcn_exp2f(sv0[4 * rq + 1]); \
        float p2 = __builtin_amdgcn_exp2f(sv0[4 * rq + 2]); \
        float p3 = __builtin_amdgcn_exp2f(sv0[4 * rq + 3]); \
        ls += (p0 + p1) + (p2 + p3); \
        pk[0][rq][0] = cvtpk(p0, p1); \
        pk[0][rq][1] = cvtpk(p2, p3); \
        float q0 = __builtin_amdgcn_exp2f(sv1[4 * rq + 0]); \
        float q1 = __builtin_amdgcn_exp2f(sv1[4 * rq + 1]); \
        float q2 = __builtin_amdgcn_exp2f(sv1[4 * rq + 2]); \
        float q3 = __builtin_amdgcn_exp2f(sv1[4 * rq + 3]); \
        ls += (q0 + q1) + (q2 + q3); \
        pk[1][rq][0] = cvtpk(q0, q1); \
        pk[1][rq][1] = cvtpk(q2, q3); \
    } \
    lsum += ls; \
    _Pragma("unroll") \
    for (int ks = 0; ks < 4; ++ks) { \
        const int kt2 = ks >> 1, q2i = ks & 1; \
        unsigned a0 = pk[kt2][2 * q2i][0], b0 = pk[kt2][2 * q2i + 1][0]; \
        unsigned a1 = pk[kt2][2 * q2i][1], b1 = pk[kt2][2 * q2i + 1][1]; \
        plswap(a0, b0); \
        plswap(a1, b1); \
        pa[ks].u[0] = a0; pa[ks].u[1] = a1; \
        pa[ks].u[2] = b0; pa[ks].u[3] = b1; \
    } }

__global__ __launch_bounds__(256, 2) void attn_mfma32(
    const ushort* __restrict__ qb, const ushort* __restrict__ kb,
    const ushort* __restrict__ vtb, ushort* __restrict__ hb)
{
    __shared__ ushort smem[16384];   // buf b: K = b*8192, V = b*8192+4096; Tr aliases [0..8192)

    const int tid = threadIdx.x;
    const int w = tid >> 6, l = tid & 63;
    const int l31 = l & 31, hi = l >> 5;
    const int lr = l >> 3, lc = l & 7;           // staging row-in-8 / chunk

    // XCD-aware decode: wg = (bh&7) + 8*(qblk + 4*(bh>>3)), qblk 0..3
    const int wg = blockIdx.x;
    const int rxcd = wg & 7, t = wg >> 3;
    const int qblk = t & 3;
    const int bh = ((t >> 2) << 3) | rxcd;

    const size_t qbase = (size_t)bh * 65536;
    const int src_bh = ((bh >> 3) & 15) ? bh - 8 : bh;   // prev-frame gather
    const size_t kvbase = (size_t)src_bh * 65536;

    // Q B-frags for both tiles: col = q = l31, k(=d) = dq*16 + hi*8 + e
    const int qrowA = qblk * 256 + w * 32 + l31;         // tile B = +128 rows
    const ushort* qpA = qb + qbase + (size_t)qrowA * 64 + hi * 8;
    const ushort* qpB = qpA + 128 * 64;
    short8 qfA[4], qfB[4];
    #pragma unroll
    for (int dq = 0; dq < 4; ++dq) {
        qfA[dq] = *(const short8*)(qpA + dq * 16);
        qfB[dq] = *(const short8*)(qpB + dq * 16);
    }

    f32x16 accA0 = {}, accA1 = {}, accB0 = {}, accB1 = {};
    float lsumA = 0.f, lsumB = 0.f;

    const int r0 = w * 16 + lr;                  // staged row (2 calls: +0, +8)
    const int ck8 = (lc ^ lr) * 8;               // inverse-swizzled chunk (ushort units)

#define STAGE_KV(ktv, b) { \
    ushort* KD = smem + (b) * 8192 + w * 1024; \
    ushort* VD = smem + (b) * 8192 + 4096 + w * 1024; \
    GLL16(kb  + kvbase + (size_t)((ktv) * 64 + r0)     * 64 + ck8, KD); \
    GLL16(kb  + kvbase + (size_t)((ktv) * 64 + r0 + 8) * 64 + ck8, KD + 512); \
    GLL16(vtb + kvbase + (size_t)r0       * 1024 + (ktv) * 64 + ck8, VD); \
    GLL16(vtb + kvbase + (size_t)(r0 + 8) * 1024 + (ktv) * 64 + ck8, VD + 512); }

    STAGE_KV(0, 0);
    __syncthreads();

    int cur = 0;
    for (int kt = 0; kt < 16; ++kt) {
        if (kt < 15) STAGE_KV(kt + 1, cur ^ 1);
        const ushort* Ks = smem + cur * 8192;
        const ushort* Vt = smem + cur * 8192 + 4096;

        // ---- S^T = K Q^T for both tiles (K frags read once) ----
        f32x16 svA0 = {}, svA1 = {}, svB0 = {}, svB1 = {};
        __builtin_amdgcn_s_setprio(1);
        #pragma unroll
        for (int dq = 0; dq < 4; ++dq) {
            short8 kf0 = *(const short8*)&Ks[SWZ(l31,      dq * 16 + hi * 8)];
            short8 kf1 = *(const short8*)&Ks[SWZ(32 + l31, dq * 16 + hi * 8)];
            svA0 = __builtin_amdgcn_mfma_f32_32x32x16_bf16(kf0, qfA[dq], svA0, 0, 0, 0);
            svA1 = __builtin_amdgcn_mfma_f32_32x32x16_bf16(kf1, qfA[dq], svA1, 0, 0, 0);
            svB0 = __builtin_amdgcn_mfma_f32_32x32x16_bf16(kf0, qfB[dq], svB0, 0, 0, 0);
            svB1 = __builtin_amdgcn_mfma_f32_32x32x16_bf16(kf1, qfB[dq], svB1, 0, 0, 0);
        }
        __builtin_amdgcn_s_setprio(0);

        // ---- p = exp2(s), pack, half-exchange (both tiles) ----
        union { u32x4 u; short8 s; } paA[4], paB[4];
        SOFTPACK(svA0, svA1, lsumA, paA);
        SOFTPACK(svB0, svB1, lsumB, paB);

        // ---- O^T += V^T P^T (V frags read once) ----
        __builtin_amdgcn_s_setprio(1);
        #pragma unroll
        for (int ks = 0; ks < 4; ++ks) {
            short8 vf0 = *(const short8*)&Vt[SWZ(l31,      ks * 16 + hi * 8)];
            short8 vf1 = *(const short8*)&Vt[SWZ(32 + l31, ks * 16 + hi * 8)];
            accA0 = __builtin_amdgcn_mfma_f32_32x32x16_bf16(vf0, paA[ks].s, accA0, 0, 0, 0);
            accA1 = __builtin_amdgcn_mfma_f32_32x32x16_bf16(vf1, paA[ks].s, accA1, 0, 0, 0);
            accB0 = __builtin_amdgcn_mfma_f32_32x32x16_bf16(vf0, paB[ks].s, accB0, 0, 0, 0);
            accB1 = __builtin_amdgcn_mfma_f32_32x32x16_bf16(vf1, paB[ks].s, accB1, 0, 0, 0);
        }
        __builtin_amdgcn_s_setprio(0);

        __syncthreads();
        cur ^= 1;
    }
#undef STAGE_KV

    // lsum = own half + partner half
    {
        unsigned au = __float_as_uint(lsumA), bu = au;
        plswap(au, bu);
        lsumA = __uint_as_float(au) + __uint_as_float(bu);
        unsigned cu2 = __float_as_uint(lsumB), du = cu2;
        plswap(cu2, du);
        lsumB = __uint_as_float(cu2) + __uint_as_float(du);
    }

    // ---- epilogue: O^T[d][q=l31] -> Tr[q][d] -> coalesced global b128 ----
    ushort* tw = smem + w * 2048;    // per-wave region (all waves past final barrier)
    const int q2 = l >> 1, ch = (l & 1) * 32;
    {
        const float inv = 1.f / lsumA;
        #pragma unroll
        for (int r = 0; r < 16; ++r) {
            const int d = (r & 3) + 8 * (r >> 2) + 4 * hi;
            tw[SWZ(l31, d)]      = f2bf(accA0[r] * inv);
            tw[SWZ(l31, 32 + d)] = f2bf(accA1[r] * inv);
        }
        const int hrow = qblk * 256 + w * 32 + q2;
        ushort* gdst = hb + ((size_t)(bh >> 3) * NTOK + hrow) * D512 + (bh & 7) * 64 + ch;
        #pragma unroll
        for (int c = 0; c < 4; ++c)
            *(u32x4*)(gdst + c * 8) = *(const u32x4*)&tw[SWZ(q2, ch + c * 8)];
    }
    __builtin_amdgcn_s_waitcnt(0);   // drain tile-A LDS reads before overwrite
    {
        const float inv = 1.f / lsumB;
        #pragma unroll
        for (int r = 0; r < 16; ++r) {
            const int d = (r & 3) + 8 * (r >> 2) + 4 * hi;
            tw[SWZ(l31, d)]      = f2bf(accB0[r] * inv);
            tw[SWZ(l31, 32 + d)] = f2bf(accB1[r] * inv);
        }
        const int hrow = qblk * 256 + 128 + w * 32 + q2;
        ushort* gdst = hb + ((size_t)(bh >> 3) * NTOK + hrow) * D512 + (bh & 7) * 64 + ch;
        #pragma unroll
        for (int c = 0; c < 4; ++c)
            *(u32x4*)(gdst + c * 8) = *(const u32x4*)&tw[SWZ(q2, ch + c * 8)];
    }
}

// ---------------------------------------------------------------------------
extern "C" void kernel_launch(void* const* d_in, const int* in_sizes, int n_in,
                              void* d_out, int out_size, void* d_ws, size_t ws_size,
                              hipStream_t stream)
{
    const float* hs = (const float*)d_in[0];
    const float* Wq = (const float*)d_in[1];
    const float* Wk = (const float*)d_in[2];
    const float* Wv = (const float*)d_in[3];
    const float* qd = (const float*)d_in[4];
    const float* qu = (const float*)d_in[5];
    const float* kd = (const float*)d_in[6];
    const float* ku = (const float*)d_in[7];
    const float* vd = (const float*)d_in[8];
    const float* vu = (const float*)d_in[9];
    const float* Wo = (const float*)d_in[10];
    const float* bo = (const float*)d_in[11];
    const float* od = (const float*)d_in[12];
    const float* ou = (const float*)d_in[13];

    ushort* wsb = (ushort*)d_ws;
    ushort* WT  = wsb;                       // 4 x 512 x 512 bf16 (q,k,v,o)
    ushort* hsb = wsb + 1048576;             // [32768][512]
    ushort* qb  = hsb + 16777216;            // [bh][n][64] * QSCALE
    ushort* kb  = qb  + 16777216;            // [bh][n][64] (un-gathered)
    ushort* vtb = kb  + 16777216;            // [bh][d][n]  (un-gathered)
    ushort* hbb = vtb + 16777216;            // [32768][512]

    float* out = (float*)d_out;

    cvt_bf16<<<dim3(8192), 256, 0, stream>>>(hs, hsb);
    fold_weights_T<<<dim3(64, 4), 256, 0, stream>>>(
        Wq, Wk, Wv, Wo, qd, qu, kd, ku, vd, vu, od, ou, WT);

    gemm_mfma<1><<<dim3(3072), 256, 0, stream>>>(
        hsb, WT, nullptr, nullptr, qb, kb, vtb);

    attn_mfma32<<<dim3(1024), 256, 0, stream>>>(qb, kb, vtb, hbb);

    gemm_mfma<0><<<dim3(1024), 256, 0, stream>>>(
        hbb, WT + 786432, bo, out, nullptr, nullptr, nullptr);
}